// Round 1
// baseline (246.551 us; speedup 1.0000x reference)
//
#include <hip/hip_runtime.h>
#include <hip/hip_bf16.h>
#include <stdint.h>

#define D_MODEL 1024
#define N_HEADS 16
#define HEAD_DIM 64
#define SEQ_LEN 2048
#define BATCH 2
#define M_TOK (BATCH * SEQ_LEN)   // 4096
#define ATT_SCALE 0.125f          // 1/sqrt(64)
#define RMS_EPS 1e-8f

typedef __bf16 bf16x8 __attribute__((ext_vector_type(8)));
typedef float f32x4 __attribute__((ext_vector_type(4)));
typedef unsigned short us8 __attribute__((ext_vector_type(8)));
typedef unsigned short us4 __attribute__((ext_vector_type(4)));

__device__ __forceinline__ float bf2f(unsigned short u) {
    union { unsigned int i; float f; } x; x.i = ((unsigned int)u) << 16; return x.f;
}
__device__ __forceinline__ unsigned short f2bf(float f) {
    union { float f; unsigned int i; } x; x.f = f;
    unsigned int i = x.i;
    return (unsigned short)((i + 0x7FFFu + ((i >> 16) & 1u)) >> 16);
}
__device__ __forceinline__ f32x4 mfma16(bf16x8 a, bf16x8 b, f32x4 c) {
    return __builtin_amdgcn_mfma_f32_16x16x32_bf16(a, b, c, 0, 0, 0);
}
// XOR swizzle for 128-byte-row LDS tiles: spreads ds_read_b128 across banks.
__device__ __forceinline__ int swz(int row, int cbyte) {
    return row * 128 + (cbyte ^ ((row & 7) << 4));
}

// ---------------- fp32 -> bf16 convert ----------------
__global__ void f2bf_kernel(const float* __restrict__ in,
                            unsigned short* __restrict__ out, int n4) {
    int i = blockIdx.x * blockDim.x + threadIdx.x;
    if (i >= n4) return;
    float4 v = reinterpret_cast<const float4*>(in)[i];
    us4 o = { f2bf(v.x), f2bf(v.y), f2bf(v.z), f2bf(v.w) };
    reinterpret_cast<us4*>(out)[i] = o;
}

// ---------------- RoPE table: tab[pos*32 + i] = (cos, sin) ----------------
__global__ void rope_tab_kernel(float2* __restrict__ tab) {
    int idx = blockIdx.x * 256 + threadIdx.x;   // 2048*32 entries
    int pos = idx >> 5, i = idx & 31;
    float inv = powf(10000.0f, -(float)(2 * i) / 64.0f);
    float ang = (float)pos * inv;
    tab[idx] = make_float2(cosf(ang), sinf(ang));
}

// ---------------- GEMM: C[m][n] = sum_k A[m][k] * B[n][k]  (all bf16 in) ----
// 128x128 tile, BK=64, 256 threads = 4 waves (2x2 of 64x64), mfma 16x16x32.
template <typename OutT, int NMAT>
__global__ __launch_bounds__(256, 2)
void gemm_bt_kernel(const unsigned short* __restrict__ A,
                    const unsigned short* __restrict__ B0,
                    const unsigned short* __restrict__ B1,
                    const unsigned short* __restrict__ B2,
                    OutT* __restrict__ C0, OutT* __restrict__ C1,
                    OutT* __restrict__ C2, int M, int N, int K) {
    __shared__ __align__(16) char lds[2 * 128 * 64 * 2];   // A tile + B tile, 32 KB
    char* Ab = lds;
    char* Bb = lds + 128 * 64 * 2;

    const unsigned short* Bm = B0;
    OutT* Cm = C0;
    if (NMAT > 1) {
        int z = blockIdx.z;
        if (z == 1) { Bm = B1; Cm = C1; }
        else if (z == 2) { Bm = B2; Cm = C2; }
    }

    const int tid = threadIdx.x;
    const int w = tid >> 6, lane = tid & 63;
    const int g = lane >> 4, c15 = lane & 15;
    const int wr = w >> 1, wc = w & 1;
    const int m0 = blockIdx.y * 128, n0 = blockIdx.x * 128;

    f32x4 acc[4][4] = {};
    us8 ar[4], br[4];
    const int NT = K >> 6;

    auto gload = [&](int kt) {
        int kbase = kt * 64;
#pragma unroll
        for (int i = 0; i < 4; ++i) {
            int u = tid * 4 + i;
            int row = u >> 3, slot = u & 7;
            ar[i] = *reinterpret_cast<const us8*>(A + (size_t)(m0 + row) * K + kbase + slot * 8);
            br[i] = *reinterpret_cast<const us8*>(Bm + (size_t)(n0 + row) * K + kbase + slot * 8);
        }
    };

    gload(0);
    for (int kt = 0; kt < NT; ++kt) {
        __syncthreads();   // previous tile's readers done
#pragma unroll
        for (int i = 0; i < 4; ++i) {
            int u = tid * 4 + i;
            int row = u >> 3, slot = u & 7;
            *reinterpret_cast<us8*>(Ab + swz(row, slot * 16)) = ar[i];
            *reinterpret_cast<us8*>(Bb + swz(row, slot * 16)) = br[i];
        }
        __syncthreads();   // staging visible
        if (kt + 1 < NT) gload(kt + 1);   // prefetch under compute

        bf16x8 af[4][2], bfr[4][2];
#pragma unroll
        for (int mi = 0; mi < 4; ++mi)
#pragma unroll
            for (int kk = 0; kk < 2; ++kk) {
                af[mi][kk]  = *reinterpret_cast<const bf16x8*>(Ab + swz(wr * 64 + mi * 16 + c15, kk * 64 + g * 16));
                bfr[mi][kk] = *reinterpret_cast<const bf16x8*>(Bb + swz(wc * 64 + mi * 16 + c15, kk * 64 + g * 16));
            }
#pragma unroll
        for (int mi = 0; mi < 4; ++mi)
#pragma unroll
            for (int nj = 0; nj < 4; ++nj)
#pragma unroll
                for (int kk = 0; kk < 2; ++kk)
                    acc[mi][nj] = mfma16(af[mi][kk], bfr[nj][kk], acc[mi][nj]);
    }

#pragma unroll
    for (int mi = 0; mi < 4; ++mi)
#pragma unroll
        for (int nj = 0; nj < 4; ++nj)
#pragma unroll
            for (int r = 0; r < 4; ++r) {
                int row = m0 + wr * 64 + mi * 16 + g * 4 + r;
                int col = n0 + wc * 64 + nj * 16 + c15;
                float v = acc[mi][nj][r];
                if constexpr (sizeof(OutT) == 2)
                    Cm[(size_t)row * N + col] = f2bf(v);
                else
                    Cm[(size_t)row * N + col] = v;
            }
}

// ---------------- RoPE + RMSNorm on q/k (in place, bf16) ----------------
// 4 lanes per (token, head) row of 64; z=0 -> q, z=1 -> k.
__global__ void rope_rms_kernel(unsigned short* __restrict__ Q,
                                unsigned short* __restrict__ Kt,
                                const float* __restrict__ qg,
                                const float* __restrict__ kg,
                                const float2* __restrict__ tab) {
    unsigned short* T = blockIdx.z ? Kt : Q;
    const float* gam = blockIdx.z ? kg : qg;
    int t = blockIdx.x * 256 + threadIdx.x;       // 262144 threads
    int rp = t >> 2, sub = t & 3;                 // rp: (token,head) pair 0..65535
    int s = (rp >> 4) & (SEQ_LEN - 1);            // seq position
    unsigned short* p = T + (size_t)rp * 64 + sub * 16;
    float f[16];
    us8 v0 = *reinterpret_cast<const us8*>(p);
    us8 v1 = *reinterpret_cast<const us8*>(p + 8);
#pragma unroll
    for (int j = 0; j < 8; ++j) { f[j] = bf2f(v0[j]); f[8 + j] = bf2f(v1[j]); }
#pragma unroll
    for (int j = 0; j < 8; ++j) {
        float2 cs = tab[s * 32 + sub * 8 + j];
        float e = f[2 * j], o = f[2 * j + 1];
        f[2 * j]     = e * cs.x - o * cs.y;
        f[2 * j + 1] = e * cs.y + o * cs.x;
    }
    float ss = 0.f;
#pragma unroll
    for (int j = 0; j < 16; ++j) ss += f[j] * f[j];
    ss += __shfl_xor(ss, 1);
    ss += __shfl_xor(ss, 2);
    float rinv = rsqrtf(ss * (1.0f / 64.0f) + RMS_EPS);
    us8 o0, o1;
#pragma unroll
    for (int j = 0; j < 8; ++j) {
        o0[j] = f2bf(f[j] * rinv * gam[sub * 16 + j]);
        o1[j] = f2bf(f[8 + j] * rinv * gam[sub * 16 + 8 + j]);
    }
    *reinterpret_cast<us8*>(p) = o0;
    *reinterpret_cast<us8*>(p + 8) = o1;
}

// ---------------- causal flash attention ----------------
// block: 256 thr = 4 waves, 64 q-rows/block (16/wave); KV tiles of 64.
__global__ __launch_bounds__(256, 2)
void attn_kernel(const unsigned short* __restrict__ Q,
                 const unsigned short* __restrict__ Kt,
                 const unsigned short* __restrict__ V,
                 unsigned short* __restrict__ O) {
    __shared__ __align__(16) char lds[8192 * 3];   // K 8K | Vt 8K | P 4x2K
    char* Kb = lds;
    char* Vtb = lds + 8192;
    char* Pb = lds + 16384;

    const int bh = blockIdx.x, b = bh >> 4, h = bh & 15;
    const int q0 = blockIdx.y * 64;
    const int tid = threadIdx.x, w = tid >> 6, lane = tid & 63;
    const int g = lane >> 4, c15 = lane & 15;
    char* Pw = Pb + w * 2048;

    const size_t base_bh = (size_t)b * SEQ_LEN * D_MODEL + (size_t)h * HEAD_DIM;

    const int qrow = q0 + w * 16 + c15;
    bf16x8 qf[2];
#pragma unroll
    for (int kk = 0; kk < 2; ++kk)
        qf[kk] = *reinterpret_cast<const bf16x8*>(Q + base_bh + (size_t)qrow * D_MODEL + kk * 32 + g * 8);

    f32x4 oacc[4] = {};
    float mrow[4], lrow[4];
#pragma unroll
    for (int r = 0; r < 4; ++r) { mrow[r] = -1e30f; lrow[r] = 0.f; }

    const int nt = q0 / 64 + 1;
    us8 kreg[2], vreg[2];
    auto gloadKV = [&](int kb) {
#pragma unroll
        for (int i = 0; i < 2; ++i) {
            int u = tid * 2 + i;
            int row = u >> 3, slot = u & 7;
            size_t ga = base_bh + (size_t)(kb + row) * D_MODEL + slot * 8;
            kreg[i] = *reinterpret_cast<const us8*>(Kt + ga);
            vreg[i] = *reinterpret_cast<const us8*>(V + ga);
        }
    };

    gloadKV(0);
    for (int it = 0; it < nt; ++it) {
        const int kb = it * 64;
        __syncthreads();   // prior iteration's LDS reads done
#pragma unroll
        for (int i = 0; i < 2; ++i) {
            int u = tid * 2 + i;
            int row = u >> 3, slot = u & 7;
            *reinterpret_cast<us8*>(Kb + swz(row, slot * 16)) = kreg[i];
#pragma unroll
            for (int j = 0; j < 8; ++j) {   // transposed V store (scalar)
                int d = slot * 8 + j;
                *reinterpret_cast<unsigned short*>(
                    Vtb + d * 128 + ((row * 2) ^ ((d & 7) << 4))) = vreg[i][j];
            }
        }
        __syncthreads();   // staging visible
        if (it + 1 < nt) gloadKV(kb + 64);

        // S = Q K^T
        f32x4 sacc[4] = {};
#pragma unroll
        for (int nj = 0; nj < 4; ++nj)
#pragma unroll
            for (int kk = 0; kk < 2; ++kk) {
                bf16x8 kf = *reinterpret_cast<const bf16x8*>(Kb + swz(nj * 16 + c15, kk * 64 + g * 16));
                sacc[nj] = mfma16(qf[kk], kf, sacc[nj]);
            }

        const bool diag = (kb == q0);
        float pval[4][4];
#pragma unroll
        for (int r = 0; r < 4; ++r) {
            int row = q0 + w * 16 + g * 4 + r;
            float mx = -1e30f;
#pragma unroll
            for (int nj = 0; nj < 4; ++nj) {
                float s = sacc[nj][r] * ATT_SCALE;
                if (diag && (kb + nj * 16 + c15 > row)) s = -1e30f;
                pval[nj][r] = s;
                mx = fmaxf(mx, s);
            }
#pragma unroll
            for (int off = 1; off < 16; off <<= 1) mx = fmaxf(mx, __shfl_xor(mx, off));
            float mnew = fmaxf(mrow[r], mx);
            float alpha = __expf(mrow[r] - mnew);
            float rsum = 0.f;
#pragma unroll
            for (int nj = 0; nj < 4; ++nj) {
                float pp = __expf(pval[nj][r] - mnew);
                pval[nj][r] = pp;
                rsum += pp;
            }
#pragma unroll
            for (int off = 1; off < 16; off <<= 1) rsum += __shfl_xor(rsum, off);
            lrow[r] = lrow[r] * alpha + rsum;
            mrow[r] = mnew;
#pragma unroll
            for (int f = 0; f < 4; ++f) oacc[f][r] = oacc[f][r] * alpha;
        }

        // stage P (bf16) to per-wave LDS region
#pragma unroll
        for (int nj = 0; nj < 4; ++nj)
#pragma unroll
            for (int r = 0; r < 4; ++r) {
                int prow = g * 4 + r, pcol = nj * 16 + c15;
                *reinterpret_cast<unsigned short*>(
                    Pw + prow * 128 + ((pcol * 2) ^ ((prow & 7) << 4))) = f2bf(pval[nj][r]);
            }
        __syncthreads();   // P visible (block-wide barrier covers wave-local hazard)

        // O += P V
        bf16x8 pf[2];
#pragma unroll
        for (int kk = 0; kk < 2; ++kk)
            pf[kk] = *reinterpret_cast<const bf16x8*>(Pw + swz(c15, kk * 64 + g * 16));
#pragma unroll
        for (int f = 0; f < 4; ++f)
#pragma unroll
            for (int kk = 0; kk < 2; ++kk) {
                bf16x8 vf = *reinterpret_cast<const bf16x8*>(Vtb + swz(f * 16 + c15, kk * 64 + g * 16));
                oacc[f] = mfma16(pf[kk], vf, oacc[f]);
            }
    }

#pragma unroll
    for (int f = 0; f < 4; ++f)
#pragma unroll
        for (int r = 0; r < 4; ++r) {
            int row = q0 + w * 16 + g * 4 + r;
            int d = f * 16 + c15;
            float v = oacc[f][r] / lrow[r];
            O[base_bh + (size_t)row * D_MODEL + d] = f2bf(v);
        }
}

// ---------------- launch ----------------
extern "C" void kernel_launch(void* const* d_in, const int* in_sizes, int n_in,
                              void* d_out, int out_size, void* d_ws, size_t ws_size,
                              hipStream_t stream) {
    const float* x  = (const float*)d_in[0];
    const float* wq = (const float*)d_in[1];
    const float* wk = (const float*)d_in[2];
    const float* wv = (const float*)d_in[3];
    const float* wo = (const float*)d_in[4];
    const float* qg = (const float*)d_in[5];
    const float* kg = (const float*)d_in[6];
    float* out = (float*)d_out;

    char* ws = (char*)d_ws;
    const size_t MB = 1024ull * 1024ull;
    unsigned short* xb  = (unsigned short*)(ws);              // 8 MB
    unsigned short* qb  = (unsigned short*)(ws + 8 * MB);     // 8 MB
    unsigned short* kb  = (unsigned short*)(ws + 16 * MB);    // 8 MB
    unsigned short* vb  = (unsigned short*)(ws + 24 * MB);    // 8 MB
    unsigned short* ab  = (unsigned short*)(ws + 32 * MB);    // 8 MB
    unsigned short* wqb = (unsigned short*)(ws + 40 * MB);    // 2 MB
    unsigned short* wkb = (unsigned short*)(ws + 42 * MB);
    unsigned short* wvb = (unsigned short*)(ws + 44 * MB);
    unsigned short* wob = (unsigned short*)(ws + 46 * MB);
    float2* tab         = (float2*)(ws + 48 * MB);            // 512 KB

    f2bf_kernel<<<4096, 256, 0, stream>>>(x, xb, M_TOK * D_MODEL / 4);
    f2bf_kernel<<<1024, 256, 0, stream>>>(wq, wqb, D_MODEL * D_MODEL / 4);
    f2bf_kernel<<<1024, 256, 0, stream>>>(wk, wkb, D_MODEL * D_MODEL / 4);
    f2bf_kernel<<<1024, 256, 0, stream>>>(wv, wvb, D_MODEL * D_MODEL / 4);
    f2bf_kernel<<<1024, 256, 0, stream>>>(wo, wob, D_MODEL * D_MODEL / 4);
    rope_tab_kernel<<<256, 256, 0, stream>>>(tab);

    gemm_bt_kernel<unsigned short, 3><<<dim3(8, 32, 3), 256, 0, stream>>>(
        xb, wqb, wkb, wvb, qb, kb, vb, M_TOK, D_MODEL, D_MODEL);

    rope_rms_kernel<<<dim3(1024, 1, 2), 256, 0, stream>>>(qb, kb, qg, kg, tab);

    attn_kernel<<<dim3(32, 32), 256, 0, stream>>>(qb, kb, vb, ab);

    gemm_bt_kernel<float, 1><<<dim3(8, 32, 1), 256, 0, stream>>>(
        ab, wob, nullptr, nullptr, out, nullptr, nullptr, M_TOK, D_MODEL, D_MODEL);
}

// Round 2
// 215.002 us; speedup vs baseline: 1.1467x; 1.1467x over previous
//
#include <hip/hip_runtime.h>
#include <hip/hip_bf16.h>
#include <stdint.h>

#define D_MODEL 1024
#define N_HEADS 16
#define HEAD_DIM 64
#define SEQ_LEN 2048
#define BATCH 2
#define M_TOK (BATCH * SEQ_LEN)   // 4096
#define NQT (SEQ_LEN / 64)        // 32 q-tiles of 64 rows
#define SCL2 0.18033688011112042f // (1/sqrt(64)) * log2(e)  -> use exp2
#define RMS_EPS 1e-8f

typedef __bf16 bf16x8 __attribute__((ext_vector_type(8)));
typedef float f32x4 __attribute__((ext_vector_type(4)));
typedef unsigned short us8 __attribute__((ext_vector_type(8)));
typedef unsigned short us4 __attribute__((ext_vector_type(4)));

__device__ __forceinline__ float bf2f(unsigned short u) {
    union { unsigned int i; float f; } x; x.i = ((unsigned int)u) << 16; return x.f;
}
__device__ __forceinline__ unsigned short f2bf(float f) {
    union { float f; unsigned int i; } x; x.f = f;
    unsigned int i = x.i;
    return (unsigned short)((i + 0x7FFFu + ((i >> 16) & 1u)) >> 16);
}
__device__ __forceinline__ f32x4 mfma16(bf16x8 a, bf16x8 b, f32x4 c) {
    return __builtin_amdgcn_mfma_f32_16x16x32_bf16(a, b, c, 0, 0, 0);
}

// async global->LDS, 16B per lane; LDS dest must be wave-uniform base (+lane*16 by HW)
#define GLOAD16(gp, lp) __builtin_amdgcn_global_load_lds( \
    (__attribute__((address_space(1))) void*)(gp), \
    (__attribute__((address_space(3))) void*)(lp), 16, 0, 0)

__device__ __forceinline__ uint32_t lds_off(void* p) {
    return (uint32_t)(uintptr_t)(__attribute__((address_space(3))) char*)p;
}
// gfx950 hardware transpose read: per 16-lane group reads a 4x16 bf16 tile,
// lane gets column (lane&15); vaddr = subtile_base + (lane&15)*8 bytes.
__device__ __forceinline__ uint2 ds_tr16(uint32_t addr) {
    uint2 r;
    asm volatile("ds_read_b64_tr_b16 %0, %1" : "=v"(r) : "v"(addr));
    return r;
}

// ---------------- fp32 -> bf16 converts ----------------
__global__ void f2bf_kernel(const float* __restrict__ in,
                            unsigned short* __restrict__ out, int n4) {
    int i = blockIdx.x * blockDim.x + threadIdx.x;
    if (i >= n4) return;
    float4 v = reinterpret_cast<const float4*>(in)[i];
    us4 o = { f2bf(v.x), f2bf(v.y), f2bf(v.z), f2bf(v.w) };
    reinterpret_cast<us4*>(out)[i] = o;
}

__global__ void f2bf_multi_kernel(const float* __restrict__ s0, const float* __restrict__ s1,
                                  const float* __restrict__ s2, const float* __restrict__ s3,
                                  unsigned short* __restrict__ d0, unsigned short* __restrict__ d1,
                                  unsigned short* __restrict__ d2, unsigned short* __restrict__ d3) {
    int i = blockIdx.x * 256 + threadIdx.x;       // 4 * 262144
    int mm = i >> 18, j = i & 262143;
    const float* s = mm == 0 ? s0 : mm == 1 ? s1 : mm == 2 ? s2 : s3;
    unsigned short* d = mm == 0 ? d0 : mm == 1 ? d1 : mm == 2 ? d2 : d3;
    float4 v = reinterpret_cast<const float4*>(s)[j];
    us4 o = { f2bf(v.x), f2bf(v.y), f2bf(v.z), f2bf(v.w) };
    reinterpret_cast<us4*>(d)[j] = o;
}

// ---------------- RoPE table: tab[pos*32 + i] = (cos, sin) ----------------
__global__ void rope_tab_kernel(float2* __restrict__ tab) {
    int idx = blockIdx.x * 256 + threadIdx.x;   // 2048*32 entries
    int pos = idx >> 5, i = idx & 31;
    float inv = powf(10000.0f, -(float)(2 * i) / 64.0f);
    float ang = (float)pos * inv;
    tab[idx] = make_float2(cosf(ang), sinf(ang));
}

// ---------------- GEMM (m97 structure): C[m][n] = sum_k A[m][k]*B[n][k] ----
// 128x128 tile, BK=64, 4 waves, linear LDS + global_load_lds width 16.
template <typename OutT, int NMAT>
__global__ __launch_bounds__(256, 2)
void gemm_bt_kernel(const unsigned short* __restrict__ A,
                    const unsigned short* __restrict__ B0,
                    const unsigned short* __restrict__ B1,
                    const unsigned short* __restrict__ B2,
                    OutT* __restrict__ C0, OutT* __restrict__ C1,
                    OutT* __restrict__ C2, int M, int N, int K) {
    __shared__ __align__(16) char lds[32768];   // A 16K | B 16K
    char* Ab = lds;
    char* Bb = lds + 16384;

    const unsigned short* Bm = B0;
    OutT* Cm = C0;
    if (NMAT > 1) {
        int z = blockIdx.z;
        if (z == 1) { Bm = B1; Cm = C1; }
        else if (z == 2) { Bm = B2; Cm = C2; }
    }

    const int tid = threadIdx.x;
    const int w = tid >> 6, lane = tid & 63;
    const int g = lane >> 4, c15 = lane & 15;
    const int wr = w >> 1, wc = w & 1;
    const int m0 = blockIdx.y * 128, n0 = blockIdx.x * 128;
    const int row_s = tid >> 3, k8 = tid & 7;

    f32x4 acc[4][4] = {};
    const int NT = K >> 6;

    for (int kt = 0; kt < NT; ++kt) {
        const int kb = kt * 64;
        __syncthreads();   // all readers of previous tile done
#pragma unroll
        for (int r = 0; r < 4; ++r) {   // 16KB per matrix = 4 rounds of 4KB
            int row = r * 32 + row_s;
            GLOAD16(A + (size_t)(m0 + row) * K + kb + k8 * 8, Ab + r * 4096 + w * 1024);
            GLOAD16(Bm + (size_t)(n0 + row) * K + kb + k8 * 8, Bb + r * 4096 + w * 1024);
        }
        __syncthreads();   // drains vmcnt -> tile visible

        bf16x8 af[4][2], bfr[4][2];
#pragma unroll
        for (int mi = 0; mi < 4; ++mi)
#pragma unroll
            for (int kk = 0; kk < 2; ++kk) {
                af[mi][kk]  = *reinterpret_cast<const bf16x8*>(Ab + (wr * 64 + mi * 16 + c15) * 128 + kk * 64 + g * 16);
                bfr[mi][kk] = *reinterpret_cast<const bf16x8*>(Bb + (wc * 64 + mi * 16 + c15) * 128 + kk * 64 + g * 16);
            }
#pragma unroll
        for (int mi = 0; mi < 4; ++mi)
#pragma unroll
            for (int nj = 0; nj < 4; ++nj)
#pragma unroll
                for (int kk = 0; kk < 2; ++kk)
                    acc[mi][nj] = mfma16(af[mi][kk], bfr[nj][kk], acc[mi][nj]);
    }

#pragma unroll
    for (int mi = 0; mi < 4; ++mi)
#pragma unroll
        for (int nj = 0; nj < 4; ++nj)
#pragma unroll
            for (int r = 0; r < 4; ++r) {
                int row = m0 + wr * 64 + mi * 16 + g * 4 + r;
                int col = n0 + wc * 64 + nj * 16 + c15;
                float v = acc[mi][nj][r];
                if constexpr (sizeof(OutT) == 2)
                    Cm[(size_t)row * N + col] = f2bf(v);
                else
                    Cm[(size_t)row * N + col] = v;
            }
}

// ---------------- RoPE + RMSNorm on q/k (in place, bf16) ----------------
__global__ void rope_rms_kernel(unsigned short* __restrict__ Q,
                                unsigned short* __restrict__ Kt,
                                const float* __restrict__ qg,
                                const float* __restrict__ kg,
                                const float2* __restrict__ tab) {
    unsigned short* T = blockIdx.z ? Kt : Q;
    const float* gam = blockIdx.z ? kg : qg;
    int t = blockIdx.x * 256 + threadIdx.x;
    int rp = t >> 2, sub = t & 3;
    int s = (rp >> 4) & (SEQ_LEN - 1);
    unsigned short* p = T + (size_t)rp * 64 + sub * 16;
    float f[16];
    us8 v0 = *reinterpret_cast<const us8*>(p);
    us8 v1 = *reinterpret_cast<const us8*>(p + 8);
#pragma unroll
    for (int j = 0; j < 8; ++j) { f[j] = bf2f(v0[j]); f[8 + j] = bf2f(v1[j]); }
#pragma unroll
    for (int j = 0; j < 8; ++j) {
        float2 cs = tab[s * 32 + sub * 8 + j];
        float e = f[2 * j], o = f[2 * j + 1];
        f[2 * j]     = e * cs.x - o * cs.y;
        f[2 * j + 1] = e * cs.y + o * cs.x;
    }
    float ss = 0.f;
#pragma unroll
    for (int j = 0; j < 16; ++j) ss += f[j] * f[j];
    ss += __shfl_xor(ss, 1);
    ss += __shfl_xor(ss, 2);
    float rinv = rsqrtf(ss * (1.0f / 64.0f) + RMS_EPS);
    us8 o0, o1;
#pragma unroll
    for (int j = 0; j < 8; ++j) {
        o0[j] = f2bf(f[j] * rinv * gam[sub * 16 + j]);
        o1[j] = f2bf(f[8 + j] * rinv * gam[sub * 16 + 8 + j]);
    }
    *reinterpret_cast<us8*>(p) = o0;
    *reinterpret_cast<us8*>(p + 8) = o1;
}

// ---------------- causal flash attention (swapped-QK, tr-read V) ----------
// 4 waves, 64 q/block (16/wave), KVBLK=64, double-buffered gload_lds staging.
// grid: (16 pairs, 32 bh). Pair t & 31-t -> every block does 33 KV tiles.
__global__ __launch_bounds__(256, 2)
void attn_kernel(const unsigned short* __restrict__ Q,
                 const unsigned short* __restrict__ Kt,
                 const unsigned short* __restrict__ V,
                 unsigned short* __restrict__ O) {
    __shared__ __align__(16) char lds[40960];  // K dbuf 16K | V dbuf 16K | P 8K
    const int bh = blockIdx.y, b = bh >> 4, h = bh & 15;
    const int tid = threadIdx.x, w = tid >> 6, lane = tid & 63;
    const int g = lane >> 4, c15 = lane & 15;
    char* Pw = lds + 32768 + w * 2048;
    const size_t base_bh = (size_t)b * SEQ_LEN * D_MODEL + (size_t)h * HEAD_DIM;
    const int krow_s = tid >> 3, kcol_s = (tid & 7) * 16;
    const int psw = (c15 & 7) << 4;

    // stage K (swizzled via pre-swizzled source) and V (subtiled [k/4][d/16][4][16])
    auto stageKV = [&](int buf, int kb) {
#pragma unroll
        for (int r = 0; r < 2; ++r) {
            int krow = r * 32 + krow_s;
            int cb = kcol_s ^ ((krow & 7) << 4);
            GLOAD16(Kt + base_bh + (size_t)(kb + krow) * D_MODEL + (cb >> 1),
                    lds + buf * 8192 + r * 4096 + w * 1024);
            int e = r * 2048 + tid * 8;               // LDS element index
            int vk = ((e >> 8) << 2) + ((e >> 4) & 3);
            int vd = (((e >> 6) & 3) << 4) + (e & 15);
            GLOAD16(V + base_bh + (size_t)(kb + vk) * D_MODEL + vd,
                    lds + 16384 + buf * 8192 + r * 4096 + w * 1024);
        }
    };

#pragma unroll 1
    for (int half = 0; half < 2; ++half) {
        const int qt = half ? (NQT - 1 - blockIdx.x) : blockIdx.x;
        const int q0 = qt * 64, nt = qt + 1;
        const int q = q0 + w * 16 + c15;              // this lane's q row
        bf16x8 qf[2];
#pragma unroll
        for (int kk = 0; kk < 2; ++kk)
            qf[kk] = *reinterpret_cast<const bf16x8*>(Q + base_bh + (size_t)q * D_MODEL + kk * 32 + g * 8);
        f32x4 oacc[4] = {};
        float mrun = -1e30f, lrun = 0.f;

        stageKV(0, 0);
        __syncthreads();
        for (int it = 0; it < nt; ++it) {
            const int cur = it & 1, kb = it * 64;
            if (it + 1 < nt) stageKV(cur ^ 1, kb + 64);   // async, drains at end barrier
            char* Kc = lds + cur * 8192;
            char* Vc = lds + 16384 + cur * 8192;

            // S^T = K Q^T : lane holds S[key = kb+nj*16+g*4+r][q = c15-row]
            f32x4 sacc[4] = {};
#pragma unroll
            for (int nj = 0; nj < 4; ++nj) {
                int kl = nj * 16 + c15, sw = (kl & 7) << 4;
#pragma unroll
                for (int kk = 0; kk < 2; ++kk) {
                    bf16x8 kf = *reinterpret_cast<const bf16x8*>(Kc + kl * 128 + ((kk * 64 + g * 16) ^ sw));
                    sacc[nj] = mfma16(kf, qf[kk], sacc[nj]);
                }
            }

            // in-lane online softmax (keys for ONE q live in this lane's regs)
            const bool diag = (it == nt - 1);
            float sv[4][4];
            float tmax = -1e30f;
#pragma unroll
            for (int nj = 0; nj < 4; ++nj)
#pragma unroll
                for (int r = 0; r < 4; ++r) {
                    float s = sacc[nj][r] * SCL2;
                    if (diag && (kb + nj * 16 + g * 4 + r > q)) s = -1e30f;
                    sv[nj][r] = s;
                    tmax = fmaxf(tmax, s);
                }
            tmax = fmaxf(tmax, __shfl_xor(tmax, 16));
            tmax = fmaxf(tmax, __shfl_xor(tmax, 32));
            float mnew = fmaxf(mrun, tmax);
            float alpha = exp2f(mrun - mnew);
            float rsum = 0.f;
#pragma unroll
            for (int nj = 0; nj < 4; ++nj) {
                us4 pw;
#pragma unroll
                for (int r = 0; r < 4; ++r) {
                    float p = exp2f(sv[nj][r] - mnew);
                    rsum += p;
                    pw[r] = f2bf(p);
                }
                // P[q=c15][key], swizzled row
                *reinterpret_cast<us4*>(Pw + c15 * 128 + ((nj * 32 + g * 8) ^ psw)) = pw;
            }
            rsum += __shfl_xor(rsum, 16);
            rsum += __shfl_xor(rsum, 32);
            lrun = lrun * alpha + rsum;
            mrun = mnew;

            // rescale O (rows q' = g*4+r need alpha from lane c15 = g*4+r)
            float ar[4];
#pragma unroll
            for (int r = 0; r < 4; ++r) ar[r] = __shfl(alpha, g * 4 + r, 16);
#pragma unroll
            for (int f = 0; f < 4; ++f)
#pragma unroll
                for (int r = 0; r < 4; ++r) oacc[f][r] *= ar[r];

            // O += P V : A = P from LDS, B = V via hardware transpose read
            bf16x8 pf[2];
#pragma unroll
            for (int kk = 0; kk < 2; ++kk)
                pf[kk] = *reinterpret_cast<const bf16x8*>(Pw + c15 * 128 + ((kk * 64 + g * 16) ^ psw));
            uint32_t vbase = lds_off(Vc) + c15 * 8;
            uint2 vt[4][2][2];
#pragma unroll
            for (int f = 0; f < 4; ++f)
#pragma unroll
                for (int kk = 0; kk < 2; ++kk)
#pragma unroll
                    for (int hh = 0; hh < 2; ++hh)
                        vt[f][kk][hh] = ds_tr16(vbase + (uint32_t)((kk * 8 + g * 2 + hh) * 512 + f * 128));
            asm volatile("s_waitcnt lgkmcnt(0)" ::: "memory");
            __builtin_amdgcn_sched_barrier(0);
#pragma unroll
            for (int f = 0; f < 4; ++f)
#pragma unroll
                for (int kk = 0; kk < 2; ++kk) {
                    union { uint32_t u[4]; bf16x8 v; } fu;
                    fu.u[0] = vt[f][kk][0].x; fu.u[1] = vt[f][kk][0].y;
                    fu.u[2] = vt[f][kk][1].x; fu.u[3] = vt[f][kk][1].y;
                    oacc[f] = mfma16(pf[kk], fu.v, oacc[f]);
                }
            __syncthreads();   // drains this wave's vmcnt (next-tile loads) + barrier
        }

        float li = 1.f / lrun;
        float lr[4];
#pragma unroll
        for (int r = 0; r < 4; ++r) lr[r] = __shfl(li, g * 4 + r, 16);
#pragma unroll
        for (int f = 0; f < 4; ++f)
#pragma unroll
            for (int r = 0; r < 4; ++r) {
                int qq = q0 + w * 16 + g * 4 + r;
                O[base_bh + (size_t)qq * D_MODEL + f * 16 + c15] = f2bf(oacc[f][r] * lr[r]);
            }
    }
}

// ---------------- launch ----------------
extern "C" void kernel_launch(void* const* d_in, const int* in_sizes, int n_in,
                              void* d_out, int out_size, void* d_ws, size_t ws_size,
                              hipStream_t stream) {
    const float* x  = (const float*)d_in[0];
    const float* wq = (const float*)d_in[1];
    const float* wk = (const float*)d_in[2];
    const float* wv = (const float*)d_in[3];
    const float* wo = (const float*)d_in[4];
    const float* qg = (const float*)d_in[5];
    const float* kg = (const float*)d_in[6];
    float* out = (float*)d_out;

    char* ws = (char*)d_ws;
    const size_t MB = 1024ull * 1024ull;
    unsigned short* xb  = (unsigned short*)(ws);              // 8 MB
    unsigned short* qb  = (unsigned short*)(ws + 8 * MB);
    unsigned short* kb  = (unsigned short*)(ws + 16 * MB);
    unsigned short* vb  = (unsigned short*)(ws + 24 * MB);
    unsigned short* ab  = (unsigned short*)(ws + 32 * MB);
    unsigned short* wqb = (unsigned short*)(ws + 40 * MB);
    unsigned short* wkb = (unsigned short*)(ws + 42 * MB);
    unsigned short* wvb = (unsigned short*)(ws + 44 * MB);
    unsigned short* wob = (unsigned short*)(ws + 46 * MB);
    float2* tab         = (float2*)(ws + 48 * MB);

    f2bf_kernel<<<4096, 256, 0, stream>>>(x, xb, M_TOK * D_MODEL / 4);
    f2bf_multi_kernel<<<4096, 256, 0, stream>>>(wq, wk, wv, wo, wqb, wkb, wvb, wob);
    rope_tab_kernel<<<256, 256, 0, stream>>>(tab);

    gemm_bt_kernel<unsigned short, 3><<<dim3(8, 32, 3), 256, 0, stream>>>(
        xb, wqb, wkb, wvb, qb, kb, vb, M_TOK, D_MODEL, D_MODEL);

    rope_rms_kernel<<<dim3(1024, 1, 2), 256, 0, stream>>>(qb, kb, qg, kg, tab);

    attn_kernel<<<dim3(16, 32), 256, 0, stream>>>(qb, kb, vb, ab);

    gemm_bt_kernel<float, 1><<<dim3(8, 32, 1), 256, 0, stream>>>(
        ab, wob, nullptr, nullptr, out, nullptr, nullptr, M_TOK, D_MODEL, D_MODEL);
}

// Round 4
// 196.588 us; speedup vs baseline: 1.2541x; 1.0937x over previous
//
#include <hip/hip_runtime.h>
#include <hip/hip_bf16.h>
#include <stdint.h>

#define D_MODEL 1024
#define N_HEADS 16
#define HEAD_DIM 64
#define SEQ_LEN 2048
#define BATCH 2
#define M_TOK (BATCH * SEQ_LEN)   // 4096
#define NQT (SEQ_LEN / 64)        // 32 q-tiles of 64 rows
#define SCL2 0.18033688011112042f // (1/sqrt(64)) * log2(e), folded into q gamma
#define RMS_EPS 1e-8f
#define DEFER_THR 11.5f           // ~8 nats in log2 units (T13)

typedef __bf16 bf16x8 __attribute__((ext_vector_type(8)));
typedef float f32x4 __attribute__((ext_vector_type(4)));
typedef unsigned short us8 __attribute__((ext_vector_type(8)));
typedef unsigned short us4 __attribute__((ext_vector_type(4)));

__device__ __forceinline__ float bf2f(unsigned short u) {
    union { unsigned int i; float f; } x; x.i = ((unsigned int)u) << 16; return x.f;
}
__device__ __forceinline__ unsigned short f2bf(float f) {
    union { float f; unsigned int i; } x; x.f = f;
    unsigned int i = x.i;
    return (unsigned short)((i + 0x7FFFu + ((i >> 16) & 1u)) >> 16);
}
__device__ __forceinline__ f32x4 mfma16(bf16x8 a, bf16x8 b, f32x4 c) {
    return __builtin_amdgcn_mfma_f32_16x16x32_bf16(a, b, c, 0, 0, 0);
}
__device__ __forceinline__ uint32_t cvtpk_bf16(float lo, float hi) {
    uint32_t r;
    asm("v_cvt_pk_bf16_f32 %0, %1, %2" : "=v"(r) : "v"(lo), "v"(hi));
    return r;
}

#define GLOAD16(gp, lp) __builtin_amdgcn_global_load_lds( \
    (__attribute__((address_space(1))) void*)(gp), \
    (__attribute__((address_space(3))) void*)(lp), 16, 0, 0)

__device__ __forceinline__ uint32_t lds_off(void* p) {
    return (uint32_t)(uintptr_t)(__attribute__((address_space(3))) char*)p;
}
__device__ __forceinline__ uint2 ds_tr16(uint32_t addr) {
    uint2 r;
    asm volatile("ds_read_b64_tr_b16 %0, %1" : "=v"(r) : "v"(addr));
    return r;
}

// ---------------- prep: fp32->bf16 converts + RoPE table [i][s] ----------
__global__ void prep_kernel(const float* __restrict__ x,  const float* __restrict__ wq,
                            const float* __restrict__ wk, const float* __restrict__ wv,
                            const float* __restrict__ wo,
                            unsigned short* __restrict__ xb,  unsigned short* __restrict__ wqb,
                            unsigned short* __restrict__ wkb, unsigned short* __restrict__ wvb,
                            unsigned short* __restrict__ wob, float2* __restrict__ tab2) {
    int bid = blockIdx.x;
    if (bid < 8192) {
        int i = bid * 256 + threadIdx.x;
        const float* s; unsigned short* d; int j;
        if (i < 1048576) { s = x; d = xb; j = i; }
        else {
            int t = i - 1048576; int mm = t >> 18; j = t & 262143;
            s = mm == 0 ? wq : mm == 1 ? wk : mm == 2 ? wv : wo;
            d = mm == 0 ? wqb : mm == 1 ? wkb : mm == 2 ? wvb : wob;
        }
        float4 v = reinterpret_cast<const float4*>(s)[j];
        us4 o = { f2bf(v.x), f2bf(v.y), f2bf(v.z), f2bf(v.w) };
        reinterpret_cast<us4*>(d)[j] = o;
    } else {
        int idx = (bid - 8192) * 256 + threadIdx.x;   // 65536 = 32 i x 2048 s
        int i = idx >> 11, sp = idx & 2047;
        float inv = powf(10000.0f, -(float)(2 * i) / 64.0f);
        float ang = (float)sp * inv;
        tab2[idx] = make_float2(cosf(ang), sinf(ang));  // tab2[i*2048 + s]
    }
}

// ---------------- fused QKV GEMM + RoPE + RMSNorm epilogue ----------------
// C[m][n] = sum_k A[m][k]*B[n][k]; 128x128 tile, BK=64, m97 2-phase structure.
// blockIdx.x: 0-7 -> q (rope+rms+prescale), 8-15 -> k (rope+rms), 16-23 -> v.
__global__ __launch_bounds__(256, 2)
void gemm_qkv_kernel(const unsigned short* __restrict__ A,
                     const unsigned short* __restrict__ Bq,
                     const unsigned short* __restrict__ Bk,
                     const unsigned short* __restrict__ Bv,
                     unsigned short* __restrict__ Cq,
                     unsigned short* __restrict__ Ck,
                     unsigned short* __restrict__ Cv,
                     const float* __restrict__ qg,
                     const float* __restrict__ kg,
                     const float2* __restrict__ tab2) {
    const int K = D_MODEL, N = D_MODEL;
    __shared__ __align__(16) char lds[32768];
    char* Ab = lds;
    char* Bb = lds + 16384;

    const int nb = blockIdx.x;
    const int mtype = nb >> 3;          // 0 q, 1 k, 2 v
    const int ncol = (nb & 7) * 128;    // col base within the 1024-wide matrix
    const unsigned short* Bm = mtype == 0 ? Bq : mtype == 1 ? Bk : Bv;
    unsigned short* Cm = mtype == 0 ? Cq : mtype == 1 ? Ck : Cv;

    const int tid = threadIdx.x;
    const int w = tid >> 6, lane = tid & 63;
    const int g = lane >> 4, c15 = lane & 15;
    const int wr = w >> 1, wc = w & 1;
    const int m0 = blockIdx.y * 128;
    const int row_s = tid >> 3, k8 = tid & 7;

    f32x4 acc[4][4] = {};
    const int NT = K >> 6;

    for (int kt = 0; kt < NT; ++kt) {
        const int kb = kt * 64;
        __syncthreads();
#pragma unroll
        for (int r = 0; r < 4; ++r) {
            int row = r * 32 + row_s;
            GLOAD16(A + (size_t)(m0 + row) * K + kb + k8 * 8, Ab + r * 4096 + w * 1024);
            GLOAD16(Bm + (size_t)(ncol + row) * K + kb + k8 * 8, Bb + r * 4096 + w * 1024);
        }
        __syncthreads();

        bf16x8 af[4][2], bfr[4][2];
#pragma unroll
        for (int mi = 0; mi < 4; ++mi)
#pragma unroll
            for (int kk = 0; kk < 2; ++kk) {
                af[mi][kk]  = *reinterpret_cast<const bf16x8*>(Ab + (wr * 64 + mi * 16 + c15) * 128 + kk * 64 + g * 16);
                bfr[mi][kk] = *reinterpret_cast<const bf16x8*>(Bb + (wc * 64 + mi * 16 + c15) * 128 + kk * 64 + g * 16);
            }
#pragma unroll
        for (int mi = 0; mi < 4; ++mi)
#pragma unroll
            for (int nj = 0; nj < 4; ++nj)
#pragma unroll
                for (int kk = 0; kk < 2; ++kk)
                    acc[mi][nj] = mfma16(af[mi][kk], bfr[nj][kk], acc[mi][nj]);
    }

    if (mtype == 2) {   // V: plain bf16 write
#pragma unroll
        for (int mi = 0; mi < 4; ++mi)
#pragma unroll
            for (int nj = 0; nj < 4; ++nj)
#pragma unroll
                for (int r = 0; r < 4; ++r) {
                    int row = m0 + wr * 64 + mi * 16 + g * 4 + r;
                    int col = ncol + wc * 64 + nj * 16 + c15;
                    Cm[(size_t)row * N + col] = f2bf(acc[mi][nj][r]);
                }
        return;
    }

    // ---- RoPE + RMSNorm epilogue (wave's 64 cols == one full head) ----
    const float* gam = mtype ? kg : qg;
    const float qsc = mtype ? 1.0f : SCL2;
    float g4[4];
#pragma unroll
    for (int nj = 0; nj < 4; ++nj) g4[nj] = gam[nj * 16 + c15] * qsc;
    const int ihalf = c15 >> 1;    // d>>1 within 16-col group

#pragma unroll
    for (int mi = 0; mi < 4; ++mi) {
        int rbase = m0 + wr * 64 + mi * 16 + g * 4;   // 4 consecutive rows
        int srow = rbase & (SEQ_LEN - 1);             // tiles never cross batch bound
        float2 cs[4][4];                              // [nj][r]
#pragma unroll
        for (int nj = 0; nj < 4; ++nj) {
            const float4* tp = reinterpret_cast<const float4*>(tab2 + (size_t)(nj * 8 + ihalf) * SEQ_LEN + srow);
            float4 lo = tp[0], hi = tp[1];
            cs[nj][0] = make_float2(lo.x, lo.y); cs[nj][1] = make_float2(lo.z, lo.w);
            cs[nj][2] = make_float2(hi.x, hi.y); cs[nj][3] = make_float2(hi.z, hi.w);
        }
        float rot[4][4];
#pragma unroll
        for (int nj = 0; nj < 4; ++nj)
#pragma unroll
            for (int r = 0; r < 4; ++r) {
                float v = acc[mi][nj][r];
                float pv = __shfl_xor(v, 1);
                float c = cs[nj][r].x, s = cs[nj][r].y;
                // even d: e*c - o*s (e=v,o=pv); odd d: e*s + o*c (e=pv,o=v)
                rot[nj][r] = (c15 & 1) ? fmaf(pv, s, v * c) : fmaf(-pv, s, v * c);
            }
#pragma unroll
        for (int r = 0; r < 4; ++r) {
            float ss = rot[0][r] * rot[0][r] + rot[1][r] * rot[1][r]
                     + rot[2][r] * rot[2][r] + rot[3][r] * rot[3][r];
            ss += __shfl_xor(ss, 1);
            ss += __shfl_xor(ss, 2);
            ss += __shfl_xor(ss, 4);
            ss += __shfl_xor(ss, 8);
            float rinv = rsqrtf(ss * (1.0f / 64.0f) + RMS_EPS);
#pragma unroll
            for (int nj = 0; nj < 4; ++nj) {
                int col = ncol + wc * 64 + nj * 16 + c15;
                Cm[(size_t)(rbase + r) * N + col] = f2bf(rot[nj][r] * rinv * g4[nj]);
            }
        }
    }
}

// ---------------- proj GEMM: 64x128 tile (512 blocks, 2/CU) --------------
__global__ __launch_bounds__(256, 2)
void gemm_proj_kernel(const unsigned short* __restrict__ A,
                      const unsigned short* __restrict__ B,
                      float* __restrict__ C) {
    const int K = D_MODEL, N = D_MODEL;
    __shared__ __align__(16) char lds[24576];   // A 8K | B 16K
    char* Ab = lds;
    char* Bb = lds + 8192;

    const int tid = threadIdx.x;
    const int w = tid >> 6, lane = tid & 63;
    const int g = lane >> 4, c15 = lane & 15;
    const int wr = w >> 1, wc = w & 1;          // 2x2 waves over 64x128
    const int m0 = blockIdx.y * 64, n0 = blockIdx.x * 128;
    const int row_s = tid >> 3, k8 = tid & 7;

    f32x4 acc[2][4] = {};
    const int NT = K >> 6;

    for (int kt = 0; kt < NT; ++kt) {
        const int kb = kt * 64;
        __syncthreads();
#pragma unroll
        for (int r = 0; r < 2; ++r) {
            int row = r * 32 + row_s;
            GLOAD16(A + (size_t)(m0 + row) * K + kb + k8 * 8, Ab + r * 4096 + w * 1024);
        }
#pragma unroll
        for (int r = 0; r < 4; ++r) {
            int row = r * 32 + row_s;
            GLOAD16(B + (size_t)(n0 + row) * K + kb + k8 * 8, Bb + r * 4096 + w * 1024);
        }
        __syncthreads();

        bf16x8 af[2][2], bfr[4][2];
#pragma unroll
        for (int mi = 0; mi < 2; ++mi)
#pragma unroll
            for (int kk = 0; kk < 2; ++kk)
                af[mi][kk] = *reinterpret_cast<const bf16x8*>(Ab + (wr * 32 + mi * 16 + c15) * 128 + kk * 64 + g * 16);
#pragma unroll
        for (int nj = 0; nj < 4; ++nj)
#pragma unroll
            for (int kk = 0; kk < 2; ++kk)
                bfr[nj][kk] = *reinterpret_cast<const bf16x8*>(Bb + (wc * 64 + nj * 16 + c15) * 128 + kk * 64 + g * 16);
#pragma unroll
        for (int mi = 0; mi < 2; ++mi)
#pragma unroll
            for (int nj = 0; nj < 4; ++nj)
#pragma unroll
                for (int kk = 0; kk < 2; ++kk)
                    acc[mi][nj] = mfma16(af[mi][kk], bfr[nj][kk], acc[mi][nj]);
    }

#pragma unroll
    for (int mi = 0; mi < 2; ++mi)
#pragma unroll
        for (int nj = 0; nj < 4; ++nj)
#pragma unroll
            for (int r = 0; r < 4; ++r) {
                int row = m0 + wr * 32 + mi * 16 + g * 4 + r;
                int col = n0 + wc * 64 + nj * 16 + c15;
                C[(size_t)row * N + col] = acc[mi][nj][r];
            }
}

// ---------------- causal flash attention (swapped-QK, tr-read V) ----------
// 4 waves, 64 q/block (16/wave), KVBLK=64, dbuf gload_lds staging.
// grid: (16 pairs, 32 bh); pair t & 31-t -> 33 KV tiles/block.
// Q pre-scaled by SCL2 in the QKV epilogue -> scores already in log2 units.
__global__ __launch_bounds__(256, 2)
void attn_kernel(const unsigned short* __restrict__ Q,
                 const unsigned short* __restrict__ Kt,
                 const unsigned short* __restrict__ V,
                 unsigned short* __restrict__ O) {
    __shared__ __align__(16) char lds[40960];  // K dbuf 16K | V dbuf 16K | P 8K
    const int bh = blockIdx.y, b = bh >> 4, h = bh & 15;
    const int tid = threadIdx.x, w = tid >> 6, lane = tid & 63;
    const int g = lane >> 4, c15 = lane & 15;
    char* Pw = lds + 32768 + w * 2048;
    const size_t base_bh = (size_t)b * SEQ_LEN * D_MODEL + (size_t)h * HEAD_DIM;
    const int krow_s = tid >> 3, kcol_s = (tid & 7) * 16;
    const int psw = (c15 & 7) << 4;

    auto stageKV = [&](int buf, int kb) {
#pragma unroll
        for (int r = 0; r < 2; ++r) {
            int krow = r * 32 + krow_s;
            int cb = kcol_s ^ ((krow & 7) << 4);
            GLOAD16(Kt + base_bh + (size_t)(kb + krow) * D_MODEL + (cb >> 1),
                    lds + buf * 8192 + r * 4096 + w * 1024);
            int e = r * 2048 + tid * 8;
            int vk = ((e >> 8) << 2) + ((e >> 4) & 3);
            int vd = (((e >> 6) & 3) << 4) + (e & 15);
            GLOAD16(V + base_bh + (size_t)(kb + vk) * D_MODEL + vd,
                    lds + 16384 + buf * 8192 + r * 4096 + w * 1024);
        }
    };

#pragma unroll 1
    for (int half = 0; half < 2; ++half) {
        const int qt = half ? (NQT - 1 - blockIdx.x) : blockIdx.x;
        const int q0 = qt * 64, nt = qt + 1;
        const int q = q0 + w * 16 + c15;
        bf16x8 qf[2];
#pragma unroll
        for (int kk = 0; kk < 2; ++kk)
            qf[kk] = *reinterpret_cast<const bf16x8*>(Q + base_bh + (size_t)q * D_MODEL + kk * 32 + g * 8);
        f32x4 oacc[4] = {};
        float mrun = -1e30f, lrun = 0.f;

        stageKV(0, 0);
        __syncthreads();
        for (int it = 0; it < nt; ++it) {
            const int cur = it & 1, kb = it * 64;
            if (it + 1 < nt) stageKV(cur ^ 1, kb + 64);
            char* Kc = lds + cur * 8192;
            char* Vc = lds + 16384 + cur * 8192;

            // S^T = K Q^T
            f32x4 sacc[4] = {};
            __builtin_amdgcn_s_setprio(1);
#pragma unroll
            for (int nj = 0; nj < 4; ++nj) {
                int kl = nj * 16 + c15, sw = (kl & 7) << 4;
#pragma unroll
                for (int kk = 0; kk < 2; ++kk) {
                    bf16x8 kf = *reinterpret_cast<const bf16x8*>(Kc + kl * 128 + ((kk * 64 + g * 16) ^ sw));
                    sacc[nj] = mfma16(kf, qf[kk], sacc[nj]);
                }
            }
            __builtin_amdgcn_s_setprio(0);

            // in-lane online softmax; scores already scaled (log2 units)
            const bool diag = (it == nt - 1);
            float sv[4][4];
            float tmax = -1e30f;
#pragma unroll
            for (int nj = 0; nj < 4; ++nj)
#pragma unroll
                for (int r = 0; r < 4; ++r) {
                    float s = sacc[nj][r];
                    if (diag && (kb + nj * 16 + g * 4 + r > q)) s = -1e30f;
                    sv[nj][r] = s;
                    tmax = fmaxf(tmax, s);
                }
            tmax = fmaxf(tmax, __shfl_xor(tmax, 16));
            tmax = fmaxf(tmax, __shfl_xor(tmax, 32));

            float alpha = 1.0f;
            if (__any(tmax > mrun + DEFER_THR)) {   // T13: defer-max
                float mnew = fmaxf(mrun, tmax);
                alpha = exp2f(mrun - mnew);
                mrun = mnew;
                float ar[4];
#pragma unroll
                for (int r = 0; r < 4; ++r) ar[r] = __shfl(alpha, g * 4 + r, 16);
#pragma unroll
                for (int f = 0; f < 4; ++f)
#pragma unroll
                    for (int r = 0; r < 4; ++r) oacc[f][r] *= ar[r];
            }

            float rsum = 0.f;
#pragma unroll
            for (int nj = 0; nj < 4; ++nj) {
                float p0 = exp2f(sv[nj][0] - mrun);
                float p1 = exp2f(sv[nj][1] - mrun);
                float p2 = exp2f(sv[nj][2] - mrun);
                float p3 = exp2f(sv[nj][3] - mrun);
                rsum += (p0 + p1) + (p2 + p3);
                uint2 pw = { cvtpk_bf16(p0, p1), cvtpk_bf16(p2, p3) };
                *reinterpret_cast<uint2*>(Pw + c15 * 128 + ((nj * 32 + g * 8) ^ psw)) = pw;
            }
            rsum += __shfl_xor(rsum, 16);
            rsum += __shfl_xor(rsum, 32);
            lrun = lrun * alpha + rsum;

            // O += P V
            bf16x8 pf[2];
#pragma unroll
            for (int kk = 0; kk < 2; ++kk)
                pf[kk] = *reinterpret_cast<const bf16x8*>(Pw + c15 * 128 + ((kk * 64 + g * 16) ^ psw));
            uint32_t vbase = lds_off(Vc) + c15 * 8;
            uint2 vt[4][2][2];
#pragma unroll
            for (int f = 0; f < 4; ++f)
#pragma unroll
                for (int kk = 0; kk < 2; ++kk)
#pragma unroll
                    for (int hh = 0; hh < 2; ++hh)
                        vt[f][kk][hh] = ds_tr16(vbase + (uint32_t)((kk * 8 + g * 2 + hh) * 512 + f * 128));
            asm volatile("s_waitcnt lgkmcnt(0)" ::: "memory");
            __builtin_amdgcn_sched_barrier(0);
            __builtin_amdgcn_s_setprio(1);
#pragma unroll
            for (int f = 0; f < 4; ++f)
#pragma unroll
                for (int kk = 0; kk < 2; ++kk) {
                    union { uint32_t u[4]; bf16x8 v; } fu;
                    fu.u[0] = vt[f][kk][0].x; fu.u[1] = vt[f][kk][0].y;
                    fu.u[2] = vt[f][kk][1].x; fu.u[3] = vt[f][kk][1].y;
                    oacc[f] = mfma16(pf[kk], fu.v, oacc[f]);
                }
            __builtin_amdgcn_s_setprio(0);
            __syncthreads();
        }

        float li = 1.f / lrun;
        float lr[4];
#pragma unroll
        for (int r = 0; r < 4; ++r) lr[r] = __shfl(li, g * 4 + r, 16);
#pragma unroll
        for (int f = 0; f < 4; ++f)
#pragma unroll
            for (int r = 0; r < 4; ++r) {
                int qq = q0 + w * 16 + g * 4 + r;
                O[base_bh + (size_t)qq * D_MODEL + f * 16 + c15] = f2bf(oacc[f][r] * lr[r]);
            }
    }
}

// ---------------- launch ----------------
extern "C" void kernel_launch(void* const* d_in, const int* in_sizes, int n_in,
                              void* d_out, int out_size, void* d_ws, size_t ws_size,
                              hipStream_t stream) {
    const float* x  = (const float*)d_in[0];
    const float* wq = (const float*)d_in[1];
    const float* wk = (const float*)d_in[2];
    const float* wv = (const float*)d_in[3];
    const float* wo = (const float*)d_in[4];
    const float* qg = (const float*)d_in[5];
    const float* kg = (const float*)d_in[6];
    float* out = (float*)d_out;

    char* ws = (char*)d_ws;
    const size_t MB = 1024ull * 1024ull;
    unsigned short* xb  = (unsigned short*)(ws);
    unsigned short* qb  = (unsigned short*)(ws + 8 * MB);
    unsigned short* kb  = (unsigned short*)(ws + 16 * MB);
    unsigned short* vb  = (unsigned short*)(ws + 24 * MB);
    unsigned short* ab  = (unsigned short*)(ws + 32 * MB);
    unsigned short* wqb = (unsigned short*)(ws + 40 * MB);
    unsigned short* wkb = (unsigned short*)(ws + 42 * MB);
    unsigned short* wvb = (unsigned short*)(ws + 44 * MB);
    unsigned short* wob = (unsigned short*)(ws + 46 * MB);
    float2* tab2        = (float2*)(ws + 48 * MB);

    prep_kernel<<<8448, 256, 0, stream>>>(x, wq, wk, wv, wo, xb, wqb, wkb, wvb, wob, tab2);

    gemm_qkv_kernel<<<dim3(24, 32), 256, 0, stream>>>(
        xb, wqb, wkb, wvb, qb, kb, vb, qg, kg, tab2);

    attn_kernel<<<dim3(16, 32), 256, 0, stream>>>(qb, kb, vb, ab);

    gemm_proj_kernel<<<dim3(8, 64), 256, 0, stream>>>(ab, wob, out);
}